// Round 1
// 428.927 us; speedup vs baseline: 1.0080x; 1.0080x over previous
//
#include <hip/hip_runtime.h>
#include <hip/hip_bf16.h>
#include <cstdint>
#include <cstddef>

// WaveKAN FFN: B=4 S=2048 D=1024 H=4096, M = B*S = 8192.
// layer1: h = mexhat((x-t1)/s1) @ wav_w1^T + silu(x) @ base_w1^T   [M,H]
// layer2: out = mexhat((h-t2)/s2) @ wav_w2^T + silu(h) @ base_w2^T [M,D]
// Branch-GEMMs concatenated along K, INTERLEAVED (k=2i+p: p=0 wav, p=1 silu).
// R2: 32x32 MFMA conflicts with BK-major LDS -> 16x16.
// R3: split-K device atomics cost +48us -> single-pass.
// R5: hoisted addressing + launch_bounds -> 803 TF/gemm, MfmaUtil 34%.
// R6: GEMM1 -> 256x256 8-phase counted-vmcnt schedule (guide T3+T4+T5):
//   - 8 waves (2Mx4N), BK=64, 128KiB LDS double-buffer, 1 block/CU.
//   - per phase: {ds_read A rowpair (+B at ph0) | stage half-tile} ->
//     s_barrier -> lgkmcnt(0) -> setprio(1) 16xMFMA setprio(0) -> s_barrier.
//   - stage lead: tile T's A staged at T-1.ph0 (other buf); tile T's B at
//     T-2.ph1/ph2 (current buf B region - safe: B reads all complete in ph0).
//   - boundary wait vmcnt(4), NEVER 0 in steady loop (T4 = the gain).
//   GEMM2 (N=1024: 256-tile grid would idle half the CUs) keeps the proven
//   128x128 kernel. T1 XCD-chunked swizzle added to both (nwg=512, %8==0).

typedef __bf16 bf16x8 __attribute__((ext_vector_type(8)));
typedef float  f32x4  __attribute__((ext_vector_type(4)));
typedef unsigned short u16x8 __attribute__((ext_vector_type(8)));

#define MH_C 0.8673250705840776f   // 2/sqrt(3) * pi^-0.25

__device__ __forceinline__ float mexhat_z(float z) {
    float z2 = z * z;
    return MH_C * (1.0f - z2) * __expf(-0.5f * z2);
}
__device__ __forceinline__ float silu_f(float x) {
    return x / (1.0f + __expf(-x));
}
__device__ __forceinline__ float silu_fast(float x) {
    return x * __builtin_amdgcn_rcpf(1.0f + __expf(-x));
}
__device__ __forceinline__ unsigned short f2bf(float f) {
    union { __hip_bfloat16 b; unsigned short u; } cv;
    cv.b = __float2bfloat16(f);
    return cv.u;
}

// Fused prep: job 0: W1c [H,2D] ilv; job 1: W2c [D,2H] ilv;
// job 2: A1 [M,2D] ilv <- mexhat((x-t1)/s1), silu(x)
template<int D, int H, int M>
__global__ __launch_bounds__(256) void prep_kernel(
        const float* __restrict__ wav_w1, const float* __restrict__ base_w1,
        const float* __restrict__ wav_w2, const float* __restrict__ base_w2,
        const float* __restrict__ x, const float* __restrict__ trans1,
        const float* __restrict__ scale1,
        unsigned short* __restrict__ W1c, unsigned short* __restrict__ W2c,
        unsigned short* __restrict__ A1) {
    constexpr int G1 = H * D / 4;
    constexpr int G2 = D * H / 4;
    int g = blockIdx.x * 256 + threadIdx.x;
    if (g < G1) {
        int idx4 = g * 4;
        int n = idx4 / D, k = idx4 - n * D;
        float4 av = *(const float4*)(wav_w1  + (size_t)n * D + k);
        float4 bv = *(const float4*)(base_w1 + (size_t)n * D + k);
        u16x8 o = { f2bf(av.x), f2bf(bv.x), f2bf(av.y), f2bf(bv.y),
                    f2bf(av.z), f2bf(bv.z), f2bf(av.w), f2bf(bv.w) };
        *(u16x8*)(W1c + (size_t)n * 2 * D + 2 * k) = o;
    } else if (g < G1 + G2) {
        int idx4 = (g - G1) * 4;
        int n = idx4 / H, k = idx4 - n * H;
        float4 av = *(const float4*)(wav_w2  + (size_t)n * H + k);
        float4 bv = *(const float4*)(base_w2 + (size_t)n * H + k);
        u16x8 o = { f2bf(av.x), f2bf(bv.x), f2bf(av.y), f2bf(bv.y),
                    f2bf(av.z), f2bf(bv.z), f2bf(av.w), f2bf(bv.w) };
        *(u16x8*)(W2c + (size_t)n * 2 * H + 2 * k) = o;
    } else {
        int idx4 = (g - G1 - G2) * 4;
        int m = idx4 / D, d = idx4 - m * D;
        float4 xv = *(const float4*)(x + (size_t)m * D + d);
        float4 t  = *(const float4*)(trans1 + d);
        float4 s  = *(const float4*)(scale1 + d);
        u16x8 o = { f2bf(mexhat_z((xv.x - t.x) / s.x)), f2bf(silu_f(xv.x)),
                    f2bf(mexhat_z((xv.y - t.y) / s.y)), f2bf(silu_f(xv.y)),
                    f2bf(mexhat_z((xv.z - t.z) / s.z)), f2bf(silu_f(xv.z)),
                    f2bf(mexhat_z((xv.w - t.w) / s.w)), f2bf(silu_f(xv.w)) };
        *(u16x8*)(A1 + (size_t)m * 2 * D + 2 * d) = o;
    }
}

// ===================== 8-phase 256x256 GEMM1 (EPI: layer-2 acts) ==========

#define AS1 __attribute__((address_space(1)))
#define AS3 __attribute__((address_space(3)))

#define SBAR() do {                                                           \
    __builtin_amdgcn_sched_barrier(0);                                        \
    asm volatile("" ::: "memory");                                            \
    __builtin_amdgcn_s_barrier();                                             \
    asm volatile("" ::: "memory");                                            \
    __builtin_amdgcn_sched_barrier(0);                                        \
} while (0)

#define WAIT_LGKM0() do {                                                     \
    asm volatile("s_waitcnt lgkmcnt(0)" ::: "memory");                        \
    __builtin_amdgcn_sched_barrier(0);                                        \
} while (0)

#define WAIT_VM(N) do {                                                       \
    asm volatile("s_waitcnt vmcnt(" #N ")" ::: "memory");                     \
    __builtin_amdgcn_sched_barrier(0);                                        \
} while (0)

#define MF16(a, b, c) __builtin_amdgcn_mfma_f32_16x16x32_bf16((a), (b), (c), 0, 0, 0)

// stage full A-tile of K-tile T (4 x 64-row slabs, 2 loads/half) -> buf T&1
#define STAGE_A(T) do {                                                       \
    const size_t ka_ = (size_t)(T) * 64;                                      \
    const int bo_ = ((T) & 1) * 16384;                                        \
    __builtin_amdgcn_global_load_lds((const AS1 void*)(gA + ka_),             \
        (AS3 void*)(lA + bo_), 16, 0, 0);                                     \
    __builtin_amdgcn_global_load_lds((const AS1 void*)(gA + ka_ + (size_t)64  * KK), \
        (AS3 void*)(lA + bo_ + 4096), 16, 0, 0);                              \
    __builtin_amdgcn_global_load_lds((const AS1 void*)(gA + ka_ + (size_t)128 * KK), \
        (AS3 void*)(lA + bo_ + 8192), 16, 0, 0);                              \
    __builtin_amdgcn_global_load_lds((const AS1 void*)(gA + ka_ + (size_t)192 * KK), \
        (AS3 void*)(lA + bo_ + 12288), 16, 0, 0);                             \
} while (0)

// stage B half H (128 rows) of K-tile T -> buf T&1
#define STAGE_B_HALF(T, H_) do {                                              \
    const size_t kb_ = (size_t)(T) * 64 + (size_t)(H_) * 128 * KK;            \
    const int bb_ = ((T) & 1) * 16384 + (H_) * 8192;                          \
    __builtin_amdgcn_global_load_lds((const AS1 void*)(gB + kb_),             \
        (AS3 void*)(lB + bb_), 16, 0, 0);                                     \
    __builtin_amdgcn_global_load_lds((const AS1 void*)(gB + kb_ + (size_t)64 * KK), \
        (AS3 void*)(lB + bb_ + 4096), 16, 0, 0);                              \
} while (0)

#define LDA(fr, SK) (*(const bf16x8*)&sA[bufo + aoff + (fr) * 1024 + (SK)])
#define LDB(fc, SK) (*(const bf16x8*)&sB[bufo + boff + (fc) * 1024 + (SK)])

#define MFMA4(P, J)                                                           \
    acc[2*(P)][J]   = MF16(pa00, bfr[J][0], acc[2*(P)][J]);                   \
    acc[2*(P)][J]   = MF16(pa01, bfr[J][1], acc[2*(P)][J]);                   \
    acc[2*(P)+1][J] = MF16(pa10, bfr[J][0], acc[2*(P)+1][J]);                 \
    acc[2*(P)+1][J] = MF16(pa11, bfr[J][1], acc[2*(P)+1][J]);

// one phase: ds-reads + (stage code) -> bar -> lgkm0 -> prio MFMA x16 -> (no
// closing bar here; caller emits it, inserting the boundary vmcnt at P==3)
#define PHASE(P, ...) do {                                                    \
    bf16x8 pa00 = LDA(2*(P),     sk0);                                        \
    bf16x8 pa01 = LDA(2*(P),     sk1);                                        \
    bf16x8 pa10 = LDA(2*(P) + 1, sk0);                                        \
    bf16x8 pa11 = LDA(2*(P) + 1, sk1);                                        \
    __VA_ARGS__                                                               \
    SBAR();                                                                   \
    WAIT_LGKM0();                                                             \
    __builtin_amdgcn_s_setprio(1);                                            \
    MFMA4(P, 0)                                                               \
    MFMA4(P, 1)                                                               \
    MFMA4(P, 2)                                                               \
    MFMA4(P, 3)                                                               \
    __builtin_amdgcn_s_setprio(0);                                            \
} while (0)

// A [M,KK] bf16, Bt [NN,KK] bf16 -> A2 [M,2*NN] bf16 ilv (layer-2 acts).
// 256x256 tile, BK=64, 512 thr = 8 waves (2x4), per-wave 128x64 out.
// XOR chunk swizzle identical to the proven kernel (0 bank conflicts).
template<int NN, int KK>
__global__ __launch_bounds__(512, 2)
void gemm1_8ph_kernel(const unsigned short* __restrict__ A,
                      const unsigned short* __restrict__ Bt,
                      unsigned short* __restrict__ A2,
                      const float* __restrict__ trans,
                      const float* __restrict__ scale) {
    constexpr int NT = KK / 64;
    __shared__ __align__(16) unsigned short sA[2 * 256 * 64];   // 64 KiB
    __shared__ __align__(16) unsigned short sB[2 * 256 * 64];   // 64 KiB

    const int tid  = threadIdx.x;
    const int lane = tid & 63;
    const int wv   = tid >> 6;         // 0..7
    const int wm   = wv >> 2;          // wave row 0..1 (128 rows each)
    const int wn   = wv & 3;           // wave col 0..3 (64 cols each)
    const int quad = lane >> 4;
    const int l15  = lane & 15;

    // T1: XCD-chunked bijective swizzle (nwg = 512, % 8 == 0)
    int bx, by;
    {
        const int gx  = gridDim.x;
        const int nwg = gx * gridDim.y;
        const int lin = blockIdx.y * gx + blockIdx.x;
        const int sw  = (lin & 7) * (nwg >> 3) + (lin >> 3);
        bx = sw % gx;
        by = sw / gx;
    }
    const int rowA = by * 256;
    const int rowB = bx * 256;

    // staging: thread covers LDS chunk c=tid of each 64-row slab; LDS linear
    // dest, source k-chunk pre-swizzled: chunk (m,j) holds global j^(m&7).
    const int gk = ((tid & 7) ^ ((tid >> 3) & 7)) * 8;
    const unsigned short* gA = A  + (size_t)(rowA + (tid >> 3)) * KK + gk;
    const unsigned short* gB = Bt + (size_t)(rowB + (tid >> 3)) * KK + gk;
    unsigned short* lA = sA + wv * 512;   // wave-uniform slice base
    unsigned short* lB = sB + wv * 512;

    // fragment LDS offsets (elements): off = m*64 + ((kcb)^(m&7))*8,
    // m&7 == l15&7 since row components are multiples of 16.
    const int sk0  = ((quad)     ^ (l15 & 7)) * 8;   // kk=0
    const int sk1  = ((4 + quad) ^ (l15 & 7)) * 8;   // kk=1
    const int aoff = (wm * 128 + l15) * 64;
    const int boff = (wn * 64  + l15) * 64;

    f32x4 acc[8][4] = {};

    // prologue: tile0 A+B, tile1 B. vmcnt(4) -> tile0 complete, tile1.B in flight.
    STAGE_A(0);
    STAGE_B_HALF(0, 0); STAGE_B_HALF(0, 1);
    STAGE_B_HALF(1, 0); STAGE_B_HALF(1, 1);
    WAIT_VM(4);
    SBAR();

    for (int t = 0; t < NT; ++t) {
        const int bufo = (t & 1) * 16384;
        bf16x8 bfr[4][2];
        // ph0: read all B frags + A rows {0,1}; stage A of t+1 (other buf)
        PHASE(0, {
            bfr[0][0] = LDB(0, sk0); bfr[0][1] = LDB(0, sk1);
            bfr[1][0] = LDB(1, sk0); bfr[1][1] = LDB(1, sk1);
            bfr[2][0] = LDB(2, sk0); bfr[2][1] = LDB(2, sk1);
            bfr[3][0] = LDB(3, sk0); bfr[3][1] = LDB(3, sk1);
            if (t + 1 < NT) STAGE_A(t + 1);
        });
        SBAR();
        // ph1: A rows {2,3}; stage B0 of t+2 into cur buf (B reads done at ph0)
        PHASE(1, { if (t + 2 < NT) STAGE_B_HALF(t + 2, 0); });
        SBAR();
        // ph2: A rows {4,5}; stage B1 of t+2
        PHASE(2, { if (t + 2 < NT) STAGE_B_HALF(t + 2, 1); });
        SBAR();
        // ph3: A rows {6,7}; boundary: counted vmcnt (never 0 in steady loop)
        PHASE(3, {});
        if (t + 2 < NT) { WAIT_VM(4); } else { WAIT_VM(0); }
        SBAR();
    }

    // epilogue: D[row=(lane>>4)*4+r][col=lane&15]; layer-2 acts -> A2 ilv
    const int colB   = bx * 256 + wn * 64;
    const int rowBse = by * 256 + wm * 128;
    #pragma unroll
    for (int j = 0; j < 4; ++j) {
        const int col  = colB + j * 16 + l15;
        const float tj = trans[col];
        const float rs = __builtin_amdgcn_rcpf(scale[col]);
        #pragma unroll
        for (int i = 0; i < 8; ++i) {
            const int row0 = rowBse + i * 16 + quad * 4;
            #pragma unroll
            for (int r = 0; r < 4; ++r) {
                float h = acc[i][j][r];
                float z = (h - tj) * rs;
                unsigned int u = (unsigned int)f2bf(mexhat_z(z))
                               | ((unsigned int)f2bf(silu_fast(h)) << 16);
                *(unsigned int*)(A2 + (size_t)(row0 + r) * (size_t)(2 * NN)
                                    + 2 * col) = u;
            }
        }
    }
}

// ================== proven 128x128 kernel (GEMM2, EPI=0) ==================
template<int EPI>
__global__ __launch_bounds__(256, 3)
void gemm_bt_kernel(const unsigned short* __restrict__ A,
                    const unsigned short* __restrict__ Bt,
                    float* __restrict__ C,
                    unsigned short* __restrict__ A2,
                    const float* __restrict__ trans,
                    const float* __restrict__ scale,
                    int N, int K) {
    __shared__ __align__(16) unsigned short sA[128 * 64];
    __shared__ __align__(16) unsigned short sB[128 * 64];

    const int tid  = threadIdx.x;
    const int lane = tid & 63;
    const int wv   = tid >> 6;
    const int wm   = wv >> 1;
    const int wn   = wv & 1;
    const int quad = lane >> 4;
    const int l15  = lane & 15;

    // T1: XCD-chunked bijective swizzle (nwg = 512, % 8 == 0)
    int bx, by;
    {
        const int gx  = gridDim.x;
        const int nwg = gx * gridDim.y;
        const int lin = blockIdx.y * gx + blockIdx.x;
        const int sw  = (lin & 7) * (nwg >> 3) + (lin >> 3);
        bx = sw % gx;
        by = sw / gx;
    }
    const int rowBase = by * 128;
    const int colBase = bx * 128;

    const unsigned short* gAp[4];
    const unsigned short* gBp[4];
    unsigned short* lAp[4];
    unsigned short* lBp[4];
    #pragma unroll
    for (int r = 0; r < 4; ++r) {
        int c  = r * 256 + wv * 64 + lane;
        int m  = c >> 3;
        int gk = ((c & 7) ^ (m & 7)) * 8;
        gAp[r] = A  + (size_t)(rowBase + m) * K + gk;
        gBp[r] = Bt + (size_t)(colBase + m) * K + gk;
        lAp[r] = sA + (size_t)(r * 256 + wv * 64) * 8;
        lBp[r] = sB + (size_t)(r * 256 + wv * 64) * 8;
    }

    int offA[2][4], offB[2][4];
    #pragma unroll
    for (int kk = 0; kk < 2; ++kk) {
        int kcb = kk * 4 + quad;
        #pragma unroll
        for (int i = 0; i < 4; ++i) {
            int m = wm * 64 + i * 16 + l15;
            offA[kk][i] = (m * 8 + (kcb ^ (m & 7))) * 8;
            int n = wn * 64 + i * 16 + l15;
            offB[kk][i] = (n * 8 + (kcb ^ (n & 7))) * 8;
        }
    }

    f32x4 acc[4][4] = {};

    for (int k0 = 0; k0 < K; k0 += 64) {
        #pragma unroll
        for (int r = 0; r < 4; ++r) {
            __builtin_amdgcn_global_load_lds(
                (const AS1 void*)(gAp[r] + k0), (AS3 void*)lAp[r], 16, 0, 0);
            __builtin_amdgcn_global_load_lds(
                (const AS1 void*)(gBp[r] + k0), (AS3 void*)lBp[r], 16, 0, 0);
        }
        __syncthreads();

        #pragma unroll
        for (int kk = 0; kk < 2; ++kk) {
            bf16x8 af[4], bfr2[4];
            #pragma unroll
            for (int i = 0; i < 4; ++i) {
                af[i]   = *(const bf16x8*)(sA + offA[kk][i]);
                bfr2[i] = *(const bf16x8*)(sB + offB[kk][i]);
            }
            #pragma unroll
            for (int i = 0; i < 4; ++i)
                #pragma unroll
                for (int j = 0; j < 4; ++j)
                    acc[i][j] = MF16(af[i], bfr2[j], acc[i][j]);
        }
        __syncthreads();
    }

    #pragma unroll
    for (int j = 0; j < 4; ++j) {
        const int col = colBase + wn * 64 + j * 16 + l15;
        float t = 0.f, rsc = 1.f;
        if (EPI == 1) { t = trans[col]; rsc = __builtin_amdgcn_rcpf(scale[col]); }
        #pragma unroll
        for (int i = 0; i < 4; ++i) {
            const int row0 = rowBase + wm * 64 + i * 16 + quad * 4;
            #pragma unroll
            for (int r = 0; r < 4; ++r) {
                float h = acc[i][j][r];
                if (EPI == 0) {
                    C[(size_t)(row0 + r) * N + col] = h;
                } else {
                    float z = (h - t) * rsc;
                    unsigned int u = (unsigned int)f2bf(mexhat_z(z))
                                   | ((unsigned int)f2bf(silu_fast(h)) << 16);
                    *(unsigned int*)(A2 + (size_t)(row0 + r) * (size_t)(2 * N)
                                        + 2 * col) = u;
                }
            }
        }
    }
}

extern "C" void kernel_launch(void* const* d_in, const int* in_sizes, int n_in,
                              void* d_out, int out_size, void* d_ws, size_t ws_size,
                              hipStream_t stream) {
    (void)in_sizes; (void)n_in; (void)out_size; (void)ws_size;
    const float* x       = (const float*)d_in[0];
    const float* scale1  = (const float*)d_in[1];
    const float* trans1  = (const float*)d_in[2];
    const float* wav_w1  = (const float*)d_in[3];
    const float* base_w1 = (const float*)d_in[4];
    const float* scale2  = (const float*)d_in[5];
    const float* trans2  = (const float*)d_in[6];
    const float* wav_w2  = (const float*)d_in[7];
    const float* base_w2 = (const float*)d_in[8];
    float* out = (float*)d_out;

    const int M = 8192, D = 1024, H = 4096;

    // workspace: W1c 16M | W2c 16M | A1 32M | A2 128M = 192 MiB
    unsigned short* W1c = (unsigned short*)d_ws;
    unsigned short* W2c = W1c + (size_t)H * 2 * D;
    unsigned short* A1  = W2c + (size_t)D * 2 * H;
    unsigned short* A2  = A1  + (size_t)M * 2 * D;

    {
        const int groups = H * D / 4 + D * H / 4 + M * D / 4;   // 4,194,304
        prep_kernel<D, H, M><<<groups / 256, 256, 0, stream>>>(
            wav_w1, base_w1, wav_w2, base_w2, x, trans1, scale1, W1c, W2c, A1);
    }
    // GEMM1 (8-phase 256^2): [M,2D] @ [H,2D]^T -> acts -> A2 [M,2H]
    {
        dim3 grid(H / 256, M / 256);   // (16, 32) = 512 wgs
        gemm1_8ph_kernel<H, 2 * D><<<grid, 512, 0, stream>>>(
            A1, W1c, A2, trans2, scale2);
    }
    // GEMM2 (proven 128^2): [M,2H] @ [D,2H]^T -> out fp32 [M,D]
    {
        dim3 grid(D / 128, M / 128);   // (8, 64) = 512 wgs
        gemm_bt_kernel<0><<<grid, 256, 0, stream>>>(A2, W2c, out, nullptr,
                                                    nullptr, nullptr, D, 2 * H);
    }
}

// Round 2
// 415.635 us; speedup vs baseline: 1.0403x; 1.0320x over previous
//
#include <hip/hip_runtime.h>
#include <hip/hip_bf16.h>
#include <cstdint>
#include <cstddef>

// WaveKAN FFN: B=4 S=2048 D=1024 H=4096, M = B*S = 8192.
// layer1: h = mexhat((x-t1)/s1) @ wav_w1^T + silu(x) @ base_w1^T   [M,H]
// layer2: out = mexhat((h-t2)/s2) @ wav_w2^T + silu(h) @ base_w2^T [M,D]
// Branch-GEMMs concatenated along K, INTERLEAVED (k=2i+p: p=0 wav, p=1 silu).
// R5: 128^2 hoisted kernel: 803 TF/gemm, MfmaUtil 34%.
// R6: 256^2 8-phase counted-vmcnt port -> SAME 34% MfmaUtil, VALU 13->26%.
//     Post-mortem: my sync macros wrapped every barrier/waitcnt in
//     asm(:::"memory") + double-sided sched_barrier(0) -- conservative
//     vmcnt drains at every fence degraded the counted schedule back to
//     drain-per-phase, and the sched walls serialized bookkeeping VALU.
// R7: template-exact sync (bare s_barrier; clobber-free waitcnt asm;
//     single sched_barrier(0) after each waitcnt per guide rule #18) +
//     per-tile hoisted LDS fragment base pointers (ds_read = base+imm).

typedef __bf16 bf16x8 __attribute__((ext_vector_type(8)));
typedef float  f32x4  __attribute__((ext_vector_type(4)));
typedef unsigned short u16x8 __attribute__((ext_vector_type(8)));

#define MH_C 0.8673250705840776f   // 2/sqrt(3) * pi^-0.25

__device__ __forceinline__ float mexhat_z(float z) {
    float z2 = z * z;
    return MH_C * (1.0f - z2) * __expf(-0.5f * z2);
}
__device__ __forceinline__ float silu_f(float x) {
    return x / (1.0f + __expf(-x));
}
__device__ __forceinline__ float silu_fast(float x) {
    return x * __builtin_amdgcn_rcpf(1.0f + __expf(-x));
}
__device__ __forceinline__ unsigned short f2bf(float f) {
    union { __hip_bfloat16 b; unsigned short u; } cv;
    cv.b = __float2bfloat16(f);
    return cv.u;
}

// Fused prep: job 0: W1c [H,2D] ilv; job 1: W2c [D,2H] ilv;
// job 2: A1 [M,2D] ilv <- mexhat((x-t1)/s1), silu(x)
template<int D, int H, int M>
__global__ __launch_bounds__(256) void prep_kernel(
        const float* __restrict__ wav_w1, const float* __restrict__ base_w1,
        const float* __restrict__ wav_w2, const float* __restrict__ base_w2,
        const float* __restrict__ x, const float* __restrict__ trans1,
        const float* __restrict__ scale1,
        unsigned short* __restrict__ W1c, unsigned short* __restrict__ W2c,
        unsigned short* __restrict__ A1) {
    constexpr int G1 = H * D / 4;
    constexpr int G2 = D * H / 4;
    int g = blockIdx.x * 256 + threadIdx.x;
    if (g < G1) {
        int idx4 = g * 4;
        int n = idx4 / D, k = idx4 - n * D;
        float4 av = *(const float4*)(wav_w1  + (size_t)n * D + k);
        float4 bv = *(const float4*)(base_w1 + (size_t)n * D + k);
        u16x8 o = { f2bf(av.x), f2bf(bv.x), f2bf(av.y), f2bf(bv.y),
                    f2bf(av.z), f2bf(bv.z), f2bf(av.w), f2bf(bv.w) };
        *(u16x8*)(W1c + (size_t)n * 2 * D + 2 * k) = o;
    } else if (g < G1 + G2) {
        int idx4 = (g - G1) * 4;
        int n = idx4 / H, k = idx4 - n * H;
        float4 av = *(const float4*)(wav_w2  + (size_t)n * H + k);
        float4 bv = *(const float4*)(base_w2 + (size_t)n * H + k);
        u16x8 o = { f2bf(av.x), f2bf(bv.x), f2bf(av.y), f2bf(bv.y),
                    f2bf(av.z), f2bf(bv.z), f2bf(av.w), f2bf(bv.w) };
        *(u16x8*)(W2c + (size_t)n * 2 * H + 2 * k) = o;
    } else {
        int idx4 = (g - G1 - G2) * 4;
        int m = idx4 / D, d = idx4 - m * D;
        float4 xv = *(const float4*)(x + (size_t)m * D + d);
        float4 t  = *(const float4*)(trans1 + d);
        float4 s  = *(const float4*)(scale1 + d);
        u16x8 o = { f2bf(mexhat_z((xv.x - t.x) / s.x)), f2bf(silu_f(xv.x)),
                    f2bf(mexhat_z((xv.y - t.y) / s.y)), f2bf(silu_f(xv.y)),
                    f2bf(mexhat_z((xv.z - t.z) / s.z)), f2bf(silu_f(xv.z)),
                    f2bf(mexhat_z((xv.w - t.w) / s.w)), f2bf(silu_f(xv.w)) };
        *(u16x8*)(A1 + (size_t)m * 2 * D + 2 * d) = o;
    }
}

// ===================== 8-phase 256x256 GEMM1 (EPI: layer-2 acts) ==========

#define AS1 __attribute__((address_space(1)))
#define AS3 __attribute__((address_space(3)))

// Template-exact sync (m201 recipe): NO memory clobbers, NO barrier
// wrapping; one sched_barrier(0) after each waitcnt (guide rule #18).
#define SBAR() __builtin_amdgcn_s_barrier()

#define WAIT_LGKM0() do {                                                     \
    asm volatile("s_waitcnt lgkmcnt(0)");                                     \
    __builtin_amdgcn_sched_barrier(0);                                        \
} while (0)

#define WAIT_VM(N) do {                                                       \
    asm volatile("s_waitcnt vmcnt(" #N ")");                                  \
    __builtin_amdgcn_sched_barrier(0);                                        \
} while (0)

#define MF16(a, b, c) __builtin_amdgcn_mfma_f32_16x16x32_bf16((a), (b), (c), 0, 0, 0)

// stage full A-tile of K-tile T (4 x 64-row slabs, 2 loads/half) -> buf T&1
#define STAGE_A(T) do {                                                       \
    const size_t ka_ = (size_t)(T) * 64;                                      \
    const int bo_ = ((T) & 1) * 16384;                                        \
    __builtin_amdgcn_global_load_lds((const AS1 void*)(gA + ka_),             \
        (AS3 void*)(lA + bo_), 16, 0, 0);                                     \
    __builtin_amdgcn_global_load_lds((const AS1 void*)(gA + ka_ + (size_t)64  * KK), \
        (AS3 void*)(lA + bo_ + 4096), 16, 0, 0);                              \
    __builtin_amdgcn_global_load_lds((const AS1 void*)(gA + ka_ + (size_t)128 * KK), \
        (AS3 void*)(lA + bo_ + 8192), 16, 0, 0);                              \
    __builtin_amdgcn_global_load_lds((const AS1 void*)(gA + ka_ + (size_t)192 * KK), \
        (AS3 void*)(lA + bo_ + 12288), 16, 0, 0);                             \
} while (0)

// stage B half H (128 rows) of K-tile T -> buf T&1
#define STAGE_B_HALF(T, H_) do {                                              \
    const size_t kb_ = (size_t)(T) * 64 + (size_t)(H_) * 128 * KK;            \
    const int bb_ = ((T) & 1) * 16384 + (H_) * 8192;                          \
    __builtin_amdgcn_global_load_lds((const AS1 void*)(gB + kb_),             \
        (AS3 void*)(lB + bb_), 16, 0, 0);                                     \
    __builtin_amdgcn_global_load_lds((const AS1 void*)(gB + kb_ + (size_t)64 * KK), \
        (AS3 void*)(lB + bb_ + 4096), 16, 0, 0);                              \
} while (0)

// fragment reads: per-tile hoisted base pointers, compile-time imm offsets
#define LDA0(fr) (*(const bf16x8*)&pA0[(fr) * 1024])
#define LDA1(fr) (*(const bf16x8*)&pA1[(fr) * 1024])
#define LDB0(fc) (*(const bf16x8*)&pB0[(fc) * 1024])
#define LDB1(fc) (*(const bf16x8*)&pB1[(fc) * 1024])

#define MFMA4(P, J)                                                           \
    acc[2*(P)][J]   = MF16(pa00, bfr[J][0], acc[2*(P)][J]);                   \
    acc[2*(P)][J]   = MF16(pa01, bfr[J][1], acc[2*(P)][J]);                   \
    acc[2*(P)+1][J] = MF16(pa10, bfr[J][0], acc[2*(P)+1][J]);                 \
    acc[2*(P)+1][J] = MF16(pa11, bfr[J][1], acc[2*(P)+1][J]);

// one phase: ds-reads + (stage code) -> bar -> lgkm0 -> prio MFMA x16.
// caller emits the closing barrier (ph3 inserts boundary vmcnt first).
#define PHASE(P, ...) do {                                                    \
    bf16x8 pa00 = LDA0(2*(P));                                                \
    bf16x8 pa01 = LDA1(2*(P));                                                \
    bf16x8 pa10 = LDA0(2*(P) + 1);                                            \
    bf16x8 pa11 = LDA1(2*(P) + 1);                                            \
    __VA_ARGS__                                                               \
    SBAR();                                                                   \
    WAIT_LGKM0();                                                             \
    __builtin_amdgcn_s_setprio(1);                                            \
    MFMA4(P, 0)                                                               \
    MFMA4(P, 1)                                                               \
    MFMA4(P, 2)                                                               \
    MFMA4(P, 3)                                                               \
    __builtin_amdgcn_s_setprio(0);                                            \
} while (0)

// A [M,KK] bf16, Bt [NN,KK] bf16 -> A2 [M,2*NN] bf16 ilv (layer-2 acts).
// 256x256 tile, BK=64, 512 thr = 8 waves (2x4), per-wave 128x64 out.
// stage lead: tile T's A staged at T-1.ph0 (other buf); tile T's B at
// T-2.ph1/ph2 (cur-buf B region, safe: all B reads complete in ph0).
// boundary wait vmcnt(4) at ph3, never 0 in the steady loop.
template<int NN, int KK>
__global__ __launch_bounds__(512, 2)
void gemm1_8ph_kernel(const unsigned short* __restrict__ A,
                      const unsigned short* __restrict__ Bt,
                      unsigned short* __restrict__ A2,
                      const float* __restrict__ trans,
                      const float* __restrict__ scale) {
    constexpr int NT = KK / 64;
    __shared__ __align__(16) unsigned short sA[2 * 256 * 64];   // 64 KiB
    __shared__ __align__(16) unsigned short sB[2 * 256 * 64];   // 64 KiB

    const int tid  = threadIdx.x;
    const int lane = tid & 63;
    const int wv   = tid >> 6;         // 0..7
    const int wm   = wv >> 2;          // wave row 0..1 (128 rows each)
    const int wn   = wv & 3;           // wave col 0..3 (64 cols each)
    const int quad = lane >> 4;
    const int l15  = lane & 15;

    // T1: XCD-chunked bijective swizzle (nwg = 512, % 8 == 0)
    int bx, by;
    {
        const int gx  = gridDim.x;
        const int nwg = gx * gridDim.y;
        const int lin = blockIdx.y * gx + blockIdx.x;
        const int sw  = (lin & 7) * (nwg >> 3) + (lin >> 3);
        bx = sw % gx;
        by = sw / gx;
    }
    const int rowA = by * 256;
    const int rowB = bx * 256;

    // staging: thread covers LDS chunk c=tid of each 64-row slab; LDS linear
    // dest, source k-chunk pre-swizzled: chunk (m,j) holds global j^(m&7).
    const int gk = ((tid & 7) ^ ((tid >> 3) & 7)) * 8;
    const unsigned short* gA = A  + (size_t)(rowA + (tid >> 3)) * KK + gk;
    const unsigned short* gB = Bt + (size_t)(rowB + (tid >> 3)) * KK + gk;
    unsigned short* lA = sA + wv * 512;   // wave-uniform slice base
    unsigned short* lB = sB + wv * 512;

    // fragment LDS offsets (elements): off = m*64 + ((kcb)^(m&7))*8,
    // m&7 == l15&7 since row components are multiples of 16.
    const int sk0  = ((quad)     ^ (l15 & 7)) * 8;   // kk=0
    const int sk1  = ((4 + quad) ^ (l15 & 7)) * 8;   // kk=1
    const int aoff = (wm * 128 + l15) * 64;
    const int boff = (wn * 64  + l15) * 64;

    f32x4 acc[8][4] = {};

    // prologue: tile0 A+B, tile1 B. vmcnt(4) -> tile0 complete, tile1.B in flight.
    STAGE_A(0);
    STAGE_B_HALF(0, 0); STAGE_B_HALF(0, 1);
    STAGE_B_HALF(1, 0); STAGE_B_HALF(1, 1);
    WAIT_VM(4);
    SBAR();

    for (int t = 0; t < NT; ++t) {
        const int bufo = (t & 1) * 16384;
        const unsigned short* pA0 = sA + bufo + aoff + sk0;
        const unsigned short* pA1 = sA + bufo + aoff + sk1;
        const unsigned short* pB0 = sB + bufo + boff + sk0;
        const unsigned short* pB1 = sB + bufo + boff + sk1;
        bf16x8 bfr[4][2];
        // ph0: read all B frags + A rows {0,1}; stage A of t+1 (other buf)
        PHASE(0, {
            bfr[0][0] = LDB0(0); bfr[0][1] = LDB1(0);
            bfr[1][0] = LDB0(1); bfr[1][1] = LDB1(1);
            bfr[2][0] = LDB0(2); bfr[2][1] = LDB1(2);
            bfr[3][0] = LDB0(3); bfr[3][1] = LDB1(3);
            if (t + 1 < NT) STAGE_A(t + 1);
        });
        SBAR();
        // ph1: A rows {2,3}; stage B0 of t+2 into cur buf (B reads done at ph0)
        PHASE(1, { if (t + 2 < NT) STAGE_B_HALF(t + 2, 0); });
        SBAR();
        // ph2: A rows {4,5}; stage B1 of t+2
        PHASE(2, { if (t + 2 < NT) STAGE_B_HALF(t + 2, 1); });
        SBAR();
        // ph3: A rows {6,7}; boundary: counted vmcnt (never 0 in steady loop)
        PHASE(3, {});
        if (t + 2 < NT) { WAIT_VM(4); } else { WAIT_VM(0); }
        SBAR();
    }

    // epilogue: D[row=(lane>>4)*4+r][col=lane&15]; layer-2 acts -> A2 ilv
    const int colB   = bx * 256 + wn * 64;
    const int rowBse = by * 256 + wm * 128;
    #pragma unroll
    for (int j = 0; j < 4; ++j) {
        const int col  = colB + j * 16 + l15;
        const float tj = trans[col];
        const float rs = __builtin_amdgcn_rcpf(scale[col]);
        #pragma unroll
        for (int i = 0; i < 8; ++i) {
            const int row0 = rowBse + i * 16 + quad * 4;
            #pragma unroll
            for (int r = 0; r < 4; ++r) {
                float h = acc[i][j][r];
                float z = (h - tj) * rs;
                unsigned int u = (unsigned int)f2bf(mexhat_z(z))
                               | ((unsigned int)f2bf(silu_fast(h)) << 16);
                *(unsigned int*)(A2 + (size_t)(row0 + r) * (size_t)(2 * NN)
                                    + 2 * col) = u;
            }
        }
    }
}

// ================== proven 128x128 kernel (GEMM2, EPI=0) ==================
template<int EPI>
__global__ __launch_bounds__(256, 3)
void gemm_bt_kernel(const unsigned short* __restrict__ A,
                    const unsigned short* __restrict__ Bt,
                    float* __restrict__ C,
                    unsigned short* __restrict__ A2,
                    const float* __restrict__ trans,
                    const float* __restrict__ scale,
                    int N, int K) {
    __shared__ __align__(16) unsigned short sA[128 * 64];
    __shared__ __align__(16) unsigned short sB[128 * 64];

    const int tid  = threadIdx.x;
    const int lane = tid & 63;
    const int wv   = tid >> 6;
    const int wm   = wv >> 1;
    const int wn   = wv & 1;
    const int quad = lane >> 4;
    const int l15  = lane & 15;

    // T1: XCD-chunked bijective swizzle (nwg = 512, % 8 == 0)
    int bx, by;
    {
        const int gx  = gridDim.x;
        const int nwg = gx * gridDim.y;
        const int lin = blockIdx.y * gx + blockIdx.x;
        const int sw  = (lin & 7) * (nwg >> 3) + (lin >> 3);
        bx = sw % gx;
        by = sw / gx;
    }
    const int rowBase = by * 128;
    const int colBase = bx * 128;

    const unsigned short* gAp[4];
    const unsigned short* gBp[4];
    unsigned short* lAp[4];
    unsigned short* lBp[4];
    #pragma unroll
    for (int r = 0; r < 4; ++r) {
        int c  = r * 256 + wv * 64 + lane;
        int m  = c >> 3;
        int gk = ((c & 7) ^ (m & 7)) * 8;
        gAp[r] = A  + (size_t)(rowBase + m) * K + gk;
        gBp[r] = Bt + (size_t)(colBase + m) * K + gk;
        lAp[r] = sA + (size_t)(r * 256 + wv * 64) * 8;
        lBp[r] = sB + (size_t)(r * 256 + wv * 64) * 8;
    }

    int offA[2][4], offB[2][4];
    #pragma unroll
    for (int kk = 0; kk < 2; ++kk) {
        int kcb = kk * 4 + quad;
        #pragma unroll
        for (int i = 0; i < 4; ++i) {
            int m = wm * 64 + i * 16 + l15;
            offA[kk][i] = (m * 8 + (kcb ^ (m & 7))) * 8;
            int n = wn * 64 + i * 16 + l15;
            offB[kk][i] = (n * 8 + (kcb ^ (n & 7))) * 8;
        }
    }

    f32x4 acc[4][4] = {};

    for (int k0 = 0; k0 < K; k0 += 64) {
        #pragma unroll
        for (int r = 0; r < 4; ++r) {
            __builtin_amdgcn_global_load_lds(
                (const AS1 void*)(gAp[r] + k0), (AS3 void*)lAp[r], 16, 0, 0);
            __builtin_amdgcn_global_load_lds(
                (const AS1 void*)(gBp[r] + k0), (AS3 void*)lBp[r], 16, 0, 0);
        }
        __syncthreads();

        #pragma unroll
        for (int kk = 0; kk < 2; ++kk) {
            bf16x8 af[4], bfr2[4];
            #pragma unroll
            for (int i = 0; i < 4; ++i) {
                af[i]   = *(const bf16x8*)(sA + offA[kk][i]);
                bfr2[i] = *(const bf16x8*)(sB + offB[kk][i]);
            }
            #pragma unroll
            for (int i = 0; i < 4; ++i)
                #pragma unroll
                for (int j = 0; j < 4; ++j)
                    acc[i][j] = MF16(af[i], bfr2[j], acc[i][j]);
        }
        __syncthreads();
    }

    #pragma unroll
    for (int j = 0; j < 4; ++j) {
        const int col = colBase + wn * 64 + j * 16 + l15;
        float t = 0.f, rsc = 1.f;
        if (EPI == 1) { t = trans[col]; rsc = __builtin_amdgcn_rcpf(scale[col]); }
        #pragma unroll
        for (int i = 0; i < 4; ++i) {
            const int row0 = rowBase + wm * 64 + i * 16 + quad * 4;
            #pragma unroll
            for (int r = 0; r < 4; ++r) {
                float h = acc[i][j][r];
                if (EPI == 0) {
                    C[(size_t)(row0 + r) * N + col] = h;
                } else {
                    float z = (h - t) * rsc;
                    unsigned int u = (unsigned int)f2bf(mexhat_z(z))
                                   | ((unsigned int)f2bf(silu_fast(h)) << 16);
                    *(unsigned int*)(A2 + (size_t)(row0 + r) * (size_t)(2 * N)
                                        + 2 * col) = u;
                }
            }
        }
    }
}

extern "C" void kernel_launch(void* const* d_in, const int* in_sizes, int n_in,
                              void* d_out, int out_size, void* d_ws, size_t ws_size,
                              hipStream_t stream) {
    (void)in_sizes; (void)n_in; (void)out_size; (void)ws_size;
    const float* x       = (const float*)d_in[0];
    const float* scale1  = (const float*)d_in[1];
    const float* trans1  = (const float*)d_in[2];
    const float* wav_w1  = (const float*)d_in[3];
    const float* base_w1 = (const float*)d_in[4];
    const float* scale2  = (const float*)d_in[5];
    const float* trans2  = (const float*)d_in[6];
    const float* wav_w2  = (const float*)d_in[7];
    const float* base_w2 = (const float*)d_in[8];
    float* out = (float*)d_out;

    const int M = 8192, D = 1024, H = 4096;

    // workspace: W1c 16M | W2c 16M | A1 32M | A2 128M = 192 MiB
    unsigned short* W1c = (unsigned short*)d_ws;
    unsigned short* W2c = W1c + (size_t)H * 2 * D;
    unsigned short* A1  = W2c + (size_t)D * 2 * H;
    unsigned short* A2  = A1  + (size_t)M * 2 * D;

    {
        const int groups = H * D / 4 + D * H / 4 + M * D / 4;   // 4,194,304
        prep_kernel<D, H, M><<<groups / 256, 256, 0, stream>>>(
            wav_w1, base_w1, wav_w2, base_w2, x, trans1, scale1, W1c, W2c, A1);
    }
    // GEMM1 (8-phase 256^2): [M,2D] @ [H,2D]^T -> acts -> A2 [M,2H]
    {
        dim3 grid(H / 256, M / 256);   // (16, 32) = 512 wgs
        gemm1_8ph_kernel<H, 2 * D><<<grid, 512, 0, stream>>>(
            A1, W1c, A2, trans2, scale2);
    }
    // GEMM2 (proven 128^2): [M,2H] @ [D,2H]^T -> out fp32 [M,D]
    {
        dim3 grid(D / 128, M / 128);   // (8, 64) = 512 wgs
        gemm_bt_kernel<0><<<grid, 256, 0, stream>>>(A2, W2c, out, nullptr,
                                                    nullptr, nullptr, D, 2 * H);
    }
}